// Round 4
// baseline (94.411 us; speedup 1.0000x reference)
//
#include <hip/hip_runtime.h>

#define HH 352
#define WW 1216
#define NBOX 16
#define KCAND 61
#define HN 88    // H/4
#define WN 304   // W/4

#define SLICES 32
#define KGROUPS 4
#define KLEN 16          // ceil(61/4)
#define THREADS 256
#define NWAVE (THREADS / 64)

// Single fused kernel: block = (slice, box, kgroup) computes a partial loss
// vector and stores it agent-scope; the last block to finish (device-scope
// counter) performs all 16 per-box argmins and writes the output.
// Deterministic: partial sums have fixed order; finalize reads all partials.
__global__ __launch_bounds__(THREADS) void fused_kernel(
    const float* __restrict__ nocs,    // (3, HN, WN)
    const float* __restrict__ dd,      // (HH, WW, 3)
    const int*   __restrict__ boxes,   // (N, 4)
    const float* __restrict__ pc,      // (N, 2)
    const float* __restrict__ bdepth,  // (N,)
    const float* __restrict__ dims,    // (N, 3)
    const float* __restrict__ intr,    // (3, 3)
    float* __restrict__ partial,       // (N, S, K) in ws
    unsigned* __restrict__ counter,    // 1 cell in ws (zeroed per call)
    float* __restrict__ out,           // (N, 3)
    int S, int nblocks)
{
    const int slice = blockIdx.x;
    const int box   = blockIdx.y;
    const int kg    = blockIdx.z;
    const int tid   = threadIdx.x;
    const int kbase = kg * KLEN;

    const int x1 = boxes[box*4+0], y1 = boxes[box*4+1];
    const int x2 = boxes[box*4+2], y2 = boxes[box*4+3];
    const int bw = x2 - x1;
    const int npix = bw * (y2 - y1);

    const float fx = intr[0], cx = intr[2], fy = intr[4], cy = intr[5];
    const float ax = (pc[box*2+0] - cx) / fx;
    const float ay = (pc[box*2+1] - cy) / fy;
    const float d0 = bdepth[box] + (0.1f * (float)kbase - 3.0f);
    const float dax = 0.1f * ax;
    const float day = 0.1f * ay;

    // exact magic-multiply division p/bw (p < 2^15, bw <= 200)
    const unsigned magic = (bw > 1) ? (0xFFFFFFFFu / (unsigned)bw + 1u) : 0u;

    float acc[KLEN];
#pragma unroll
    for (int k = 0; k < KLEN; ++k) acc[k] = 0.f;

    const int stride = S * THREADS;
    for (int p = slice * THREADS + tid; p < npix; p += stride) {
        unsigned q = (bw > 1) ? __umulhi((unsigned)p, magic) : (unsigned)p;
        const int r   = p - (int)q * bw;
        const int row = y1 + (int)q;
        const int x   = x1 + r;

        const float* dp = dd + ((size_t)row * WW + x) * 3;
        const float dz = dp[2];
        if (dz < 1.0f) continue;   // empty mask

        // bilinear 4x upsample (half-pixel, clamp-to-edge)
        const int ry  = row & 3;
        const int yy0 = (row >> 2) + ((ry >= 2) ? 0 : -1);
        const float wy = 0.125f + 0.25f * (float)((ry + 2) & 3);
        const int ya = max(yy0, 0);
        const int yb = min(yy0 + 1, HN - 1);

        const int rx  = x & 3;
        const int xx0 = (x >> 2) + ((rx >= 2) ? 0 : -1);
        const float wx = 0.125f + 0.25f * (float)((rx + 2) & 3);
        const int xa = max(xx0, 0);
        const int xb = min(xx0 + 1, WN - 1);

        float b[3];
#pragma unroll
        for (int c = 0; c < 3; ++c) {
            const float* np_ = nocs + c * (HN * WN);
            const float v00 = np_[ya*WN + xa], v01 = np_[ya*WN + xb];
            const float v10 = np_[yb*WN + xa], v11 = np_[yb*WN + xb];
            const float v0 = v00 + (v01 - v00) * wx;
            const float v1 = v10 + (v11 - v10) * wx;
            b[c] = (v0 + (v1 - v0) * wy) - dp[c];
        }

        float t0 = fmaf(ax, d0, b[0]);
        float t1 = fmaf(ay, d0, b[1]);
        float t2 = b[2] + d0;
#pragma unroll
        for (int k = 0; k < KLEN; ++k) {
            acc[k] += fabsf(t0) + fabsf(t1) + fabsf(t2);
            t0 += dax;
            t1 += day;
            t2 += 0.1f;
        }
    }

    // block reduce: per-wave shuffle, lane0 -> LDS, then cross-wave sum
    const int lane = tid & 63;
    const int wave = tid >> 6;
    __shared__ float wbuf[NWAVE][KLEN];
    __shared__ int lastflag;
#pragma unroll
    for (int k = 0; k < KLEN; ++k) {
        float v = acc[k];
        for (int off = 32; off; off >>= 1) v += __shfl_xor(v, off, 64);
        if (lane == 0) wbuf[wave][k] = v;
    }
    __syncthreads();
    if (tid < KLEN && kbase + tid < KCAND) {
        float s = 0.f;
#pragma unroll
        for (int w = 0; w < NWAVE; ++w) s += wbuf[w][tid];
        __hip_atomic_store(&partial[((size_t)box * S + slice) * KCAND + (kbase + tid)],
                           s, __ATOMIC_RELAXED, __HIP_MEMORY_SCOPE_AGENT);
    }
    // tid<16 stores and tid==0 RMW are in the same wave's instruction stream:
    // the release RMW orders the partial stores before the count is visible.
    if (tid == 0) {
        unsigned prev = __hip_atomic_fetch_add(counter, 1u, __ATOMIC_ACQ_REL,
                                               __HIP_MEMORY_SCOPE_AGENT);
        lastflag = (prev == (unsigned)(nblocks - 1)) ? 1 : 0;
    }
    __syncthreads();
    if (!lastflag) return;

    // ---- last block: finalize all boxes (4 waves x 4 boxes each) ----
    for (int b2 = wave; b2 < NBOX; b2 += NWAVE) {
        float loss = INFINITY;
        int kk = lane;
        if (lane < KCAND) {
            float s = 0.f;
            for (int sl = 0; sl < S; ++sl)
                s += __hip_atomic_load(&partial[((size_t)b2 * S + sl) * KCAND + lane],
                                       __ATOMIC_RELAXED, __HIP_MEMORY_SCOPE_AGENT);
            loss = s;
        }
        // wave argmin, ties -> smaller k (matches jnp.argmin)
        for (int off = 1; off < 64; off <<= 1) {
            const float ol = __shfl_xor(loss, off, 64);
            const int   ok = __shfl_xor(kk,   off, 64);
            if (ol < loss || (ol == loss && ok < kk)) { loss = ol; kk = ok; }
        }
        if (lane == 0) {
            const float dk  = bdepth[b2] + (0.1f * (float)kk - 3.0f);
            const float axv = (pc[b2*2+0] - cx) / fx;
            const float ayv = (pc[b2*2+1] - cy) / fy;
            out[b2*3+0] = axv * dk;
            out[b2*3+1] = ayv * dk + dims[b2*3+1] * 0.5f;
            out[b2*3+2] = dk;
        }
    }
}

extern "C" void kernel_launch(void* const* d_in, const int* in_sizes, int n_in,
                              void* d_out, int out_size, void* d_ws, size_t ws_size,
                              hipStream_t stream) {
    const float* nocs  = (const float*)d_in[0];
    const float* dd    = (const float*)d_in[1];
    const int*   boxes = (const int*)d_in[2];
    const float* pc    = (const float*)d_in[3];
    const float* bd    = (const float*)d_in[4];
    const float* dims  = (const float*)d_in[5];
    const float* intr  = (const float*)d_in[6];
    float* out = (float*)d_out;

    unsigned* counter = (unsigned*)d_ws;                       // 4B @ offset 0
    float* partial    = (float*)((char*)d_ws + 256);           // aligned

    int S = SLICES;
    while (S > 1 && 256 + (size_t)NBOX * S * KCAND * sizeof(float) > ws_size) S >>= 1;
    const int nblocks = S * NBOX * KGROUPS;

    hipMemsetAsync(counter, 0, sizeof(unsigned), stream);      // graph-safe node

    fused_kernel<<<dim3(S, NBOX, KGROUPS), THREADS, 0, stream>>>(
        nocs, dd, boxes, pc, bd, dims, intr, partial, counter, out, S, nblocks);
}

// Round 5
// 22.871 us; speedup vs baseline: 4.1279x; 4.1279x over previous
//
#include <hip/hip_runtime.h>

#define HH 352
#define WW 1216
#define NBOX 16
#define KCAND 61
#define HN 88    // H/4
#define WN 304   // W/4

#define SLICES 16
#define KGROUPS 4
#define KLEN 16          // ceil(61/4)
#define THREADS 256
#define NWAVE (THREADS / 64)

// Kernel 1: block = (slice, box, kgroup). Each thread accumulates KLEN
// candidate losses over a strided subset of the box's pixels, block-reduces,
// and writes partial[box][slice][k]. Deterministic (no atomics).
__global__ __launch_bounds__(THREADS) void loss_partial_kernel(
    const float* __restrict__ nocs,    // (3, HN, WN)
    const float* __restrict__ dd,      // (HH, WW, 3)
    const int*   __restrict__ boxes,   // (N, 4)
    const float* __restrict__ pc,      // (N, 2)
    const float* __restrict__ bdepth,  // (N,)
    const float* __restrict__ intr,    // (3, 3)
    float* __restrict__ partial,       // (N, S, K)
    int S)
{
    const int slice = blockIdx.x;
    const int box   = blockIdx.y;
    const int kg    = blockIdx.z;
    const int tid   = threadIdx.x;
    const int kbase = kg * KLEN;

    const int x1 = boxes[box*4+0], y1 = boxes[box*4+1];
    const int x2 = boxes[box*4+2], y2 = boxes[box*4+3];
    const int bw = x2 - x1;
    const int npix = bw * (y2 - y1);

    const float fx = intr[0], cx = intr[2], fy = intr[4], cy = intr[5];
    const float ax = (pc[box*2+0] - cx) / fx;
    const float ay = (pc[box*2+1] - cy) / fy;
    const float d0 = bdepth[box] + (0.1f * (float)kbase - 3.0f);
    const float dax = 0.1f * ax;
    const float day = 0.1f * ay;

    // exact magic-multiply division p/bw (p < 2^15, bw <= 200)
    const unsigned magic = (bw > 1) ? (0xFFFFFFFFu / (unsigned)bw + 1u) : 0u;

    float acc[KLEN];
#pragma unroll
    for (int k = 0; k < KLEN; ++k) acc[k] = 0.f;

    const int stride = S * THREADS;
    for (int p = slice * THREADS + tid; p < npix; p += stride) {
        unsigned q = (bw > 1) ? __umulhi((unsigned)p, magic) : (unsigned)p;
        const int r   = p - (int)q * bw;
        const int row = y1 + (int)q;
        const int x   = x1 + r;

        const float* dp = dd + ((size_t)row * WW + x) * 3;
        const float dz = dp[2];
        if (dz < 1.0f) continue;   // empty mask

        // bilinear 4x upsample (half-pixel, clamp-to-edge)
        const int ry  = row & 3;
        const int yy0 = (row >> 2) + ((ry >= 2) ? 0 : -1);
        const float wy = 0.125f + 0.25f * (float)((ry + 2) & 3);
        const int ya = max(yy0, 0);
        const int yb = min(yy0 + 1, HN - 1);

        const int rx  = x & 3;
        const int xx0 = (x >> 2) + ((rx >= 2) ? 0 : -1);
        const float wx = 0.125f + 0.25f * (float)((rx + 2) & 3);
        const int xa = max(xx0, 0);
        const int xb = min(xx0 + 1, WN - 1);

        float b[3];
#pragma unroll
        for (int c = 0; c < 3; ++c) {
            const float* np_ = nocs + c * (HN * WN);
            const float v00 = np_[ya*WN + xa], v01 = np_[ya*WN + xb];
            const float v10 = np_[yb*WN + xa], v11 = np_[yb*WN + xb];
            const float v0 = v00 + (v01 - v00) * wx;
            const float v1 = v10 + (v11 - v10) * wx;
            b[c] = (v0 + (v1 - v0) * wy) - dp[c];
        }

        float t0 = fmaf(ax, d0, b[0]);
        float t1 = fmaf(ay, d0, b[1]);
        float t2 = b[2] + d0;
#pragma unroll
        for (int k = 0; k < KLEN; ++k) {
            acc[k] += fabsf(t0) + fabsf(t1) + fabsf(t2);
            t0 += dax;
            t1 += day;
            t2 += 0.1f;
        }
    }

    // block reduce: per-wave shuffle, lane0 -> LDS, then cross-wave sum
    const int lane = tid & 63;
    const int wave = tid >> 6;
    __shared__ float wbuf[NWAVE][KLEN];
#pragma unroll
    for (int k = 0; k < KLEN; ++k) {
        float v = acc[k];
        for (int off = 32; off; off >>= 1) v += __shfl_xor(v, off, 64);
        if (lane == 0) wbuf[wave][k] = v;
    }
    __syncthreads();
    if (tid < KLEN && kbase + tid < KCAND) {
        float s = 0.f;
#pragma unroll
        for (int w = 0; w < NWAVE; ++w) s += wbuf[w][tid];
        partial[((size_t)box * S + slice) * KCAND + (kbase + tid)] = s;
    }
}

// Kernel 2: per-box slice-sum + wave argmin (first-index tie-break) + output.
__global__ __launch_bounds__(64) void finalize_kernel(
    const float* __restrict__ partial,  // (N, S, K)
    const float* __restrict__ pc,
    const float* __restrict__ bdepth,
    const float* __restrict__ dims,     // (N,3)
    const float* __restrict__ intr,
    float* __restrict__ out,            // (N,3)
    int S)
{
    const int box  = blockIdx.x;
    const int lane = threadIdx.x;

    float loss = INFINITY;
    int kk = lane;
    if (lane < KCAND) {
        float s = 0.f;
        for (int sl = 0; sl < S; ++sl)
            s += partial[((size_t)box * S + sl) * KCAND + lane];
        loss = s;
    }
    for (int off = 1; off < 64; off <<= 1) {
        const float ol = __shfl_xor(loss, off, 64);
        const int   ok = __shfl_xor(kk,   off, 64);
        if (ol < loss || (ol == loss && ok < kk)) { loss = ol; kk = ok; }
    }
    if (lane == 0) {
        const float fx = intr[0], cx = intr[2], fy = intr[4], cy = intr[5];
        const float dk = bdepth[box] + (0.1f * (float)kk - 3.0f);
        const float axv = (pc[box*2+0] - cx) / fx;
        const float ayv = (pc[box*2+1] - cy) / fy;
        out[box*3+0] = axv * dk;
        out[box*3+1] = ayv * dk + dims[box*3+1] * 0.5f;
        out[box*3+2] = dk;
    }
}

extern "C" void kernel_launch(void* const* d_in, const int* in_sizes, int n_in,
                              void* d_out, int out_size, void* d_ws, size_t ws_size,
                              hipStream_t stream) {
    const float* nocs  = (const float*)d_in[0];
    const float* dd    = (const float*)d_in[1];
    const int*   boxes = (const int*)d_in[2];
    const float* pc    = (const float*)d_in[3];
    const float* bd    = (const float*)d_in[4];
    const float* dims  = (const float*)d_in[5];
    const float* intr  = (const float*)d_in[6];
    float* out     = (float*)d_out;
    float* partial = (float*)d_ws;

    int S = SLICES;
    while (S > 1 && (size_t)NBOX * S * KCAND * sizeof(float) > ws_size) S >>= 1;

    loss_partial_kernel<<<dim3(S, NBOX, KGROUPS), THREADS, 0, stream>>>(
        nocs, dd, boxes, pc, bd, intr, partial, S);
    finalize_kernel<<<NBOX, 64, 0, stream>>>(
        partial, pc, bd, dims, intr, out, S);
}

// Round 6
// 22.477 us; speedup vs baseline: 4.2004x; 1.0175x over previous
//
#include <hip/hip_runtime.h>

#define HH 352
#define WW 1216
#define NBOX 16
#define KCAND 61
#define HN 88    // H/4
#define WN 304   // W/4

#define SLICES 8
#define KGROUPS 2
#define KLEN 32          // ceil(61/2), padded
#define THREADS 256
#define NWAVE (THREADS / 64)

// Kernel 1: block = (slice, box, kgroup). Each thread accumulates KLEN
// candidate losses over a strided subset of the box's pixels, block-reduces,
// and writes partial[box][k][slice] (slice-contiguous for kernel 2).
// Deterministic (no atomics). Grid = 8*16*2 = 256 blocks = 1/CU.
__global__ __launch_bounds__(THREADS) void loss_partial_kernel(
    const float* __restrict__ nocs,    // (3, HN, WN)
    const float* __restrict__ dd,      // (HH, WW, 3)
    const int*   __restrict__ boxes,   // (N, 4)
    const float* __restrict__ pc,      // (N, 2)
    const float* __restrict__ bdepth,  // (N,)
    const float* __restrict__ intr,    // (3, 3)
    float* __restrict__ partial,       // (N, K, S)
    int S)
{
    const int slice = blockIdx.x;
    const int box   = blockIdx.y;
    const int kg    = blockIdx.z;
    const int tid   = threadIdx.x;
    const int kbase = kg * KLEN;

    const int x1 = boxes[box*4+0], y1 = boxes[box*4+1];
    const int x2 = boxes[box*4+2], y2 = boxes[box*4+3];
    const int bw = x2 - x1;
    const int npix = bw * (y2 - y1);

    const float fx = intr[0], cx = intr[2], fy = intr[4], cy = intr[5];
    const float ax = (pc[box*2+0] - cx) / fx;
    const float ay = (pc[box*2+1] - cy) / fy;
    const float d0 = bdepth[box] + (0.1f * (float)kbase - 3.0f);
    const float dax = 0.1f * ax;
    const float day = 0.1f * ay;

    // exact magic-multiply division p/bw (p < 2^15, bw <= 200)
    const unsigned magic = (bw > 1) ? (0xFFFFFFFFu / (unsigned)bw + 1u) : 0u;

    float acc[KLEN];
#pragma unroll
    for (int k = 0; k < KLEN; ++k) acc[k] = 0.f;

    const int stride = S * THREADS;
    for (int p = slice * THREADS + tid; p < npix; p += stride) {
        unsigned q = (bw > 1) ? __umulhi((unsigned)p, magic) : (unsigned)p;
        const int r   = p - (int)q * bw;
        const int row = y1 + (int)q;
        const int x   = x1 + r;

        const float* dp = dd + ((size_t)row * WW + x) * 3;
        const float dz = dp[2];
        if (dz < 1.0f) continue;   // empty mask

        // bilinear 4x upsample (half-pixel, clamp-to-edge)
        const int ry  = row & 3;
        const int yy0 = (row >> 2) + ((ry >= 2) ? 0 : -1);
        const float wy = 0.125f + 0.25f * (float)((ry + 2) & 3);
        const int ya = max(yy0, 0);
        const int yb = min(yy0 + 1, HN - 1);

        const int rx  = x & 3;
        const int xx0 = (x >> 2) + ((rx >= 2) ? 0 : -1);
        const float wx = 0.125f + 0.25f * (float)((rx + 2) & 3);
        const int xa = max(xx0, 0);
        const int xb = min(xx0 + 1, WN - 1);

        float b[3];
#pragma unroll
        for (int c = 0; c < 3; ++c) {
            const float* np_ = nocs + c * (HN * WN);
            const float v00 = np_[ya*WN + xa], v01 = np_[ya*WN + xb];
            const float v10 = np_[yb*WN + xa], v11 = np_[yb*WN + xb];
            const float v0 = v00 + (v01 - v00) * wx;
            const float v1 = v10 + (v11 - v10) * wx;
            b[c] = (v0 + (v1 - v0) * wy) - dp[c];
        }

        float t0 = fmaf(ax, d0, b[0]);
        float t1 = fmaf(ay, d0, b[1]);
        float t2 = b[2] + d0;
#pragma unroll
        for (int k = 0; k < KLEN; ++k) {
            acc[k] += fabsf(t0) + fabsf(t1) + fabsf(t2);
            t0 += dax;
            t1 += day;
            t2 += 0.1f;
        }
    }

    // block reduce: per-wave shuffle, lane0 -> LDS, then cross-wave sum
    const int lane = tid & 63;
    const int wave = tid >> 6;
    __shared__ float wbuf[NWAVE][KLEN];
#pragma unroll
    for (int k = 0; k < KLEN; ++k) {
        float v = acc[k];
        for (int off = 32; off; off >>= 1) v += __shfl_xor(v, off, 64);
        if (lane == 0) wbuf[wave][k] = v;
    }
    __syncthreads();
    if (tid < KLEN && kbase + tid < KCAND) {
        float s = 0.f;
#pragma unroll
        for (int w = 0; w < NWAVE; ++w) s += wbuf[w][tid];
        // (box, k, slice) layout: kernel2 reads S contiguous floats per k
        partial[((size_t)box * KCAND + (kbase + tid)) * S + slice] = s;
    }
}

// Kernel 2: per-box slice-sum (contiguous, vectorizable) + wave argmin
// (first-index tie-break) + output write.
__global__ __launch_bounds__(64) void finalize_kernel(
    const float* __restrict__ partial,  // (N, K, S)
    const float* __restrict__ pc,
    const float* __restrict__ bdepth,
    const float* __restrict__ dims,     // (N,3)
    const float* __restrict__ intr,
    float* __restrict__ out,            // (N,3)
    int S)
{
    const int box  = blockIdx.x;
    const int lane = threadIdx.x;

    float loss = INFINITY;
    int kk = lane;
    if (lane < KCAND) {
        const float* p = partial + ((size_t)box * KCAND + lane) * S;
        float s = 0.f;
#pragma unroll 8
        for (int sl = 0; sl < S; ++sl) s += p[sl];
        loss = s;
    }
    for (int off = 1; off < 64; off <<= 1) {
        const float ol = __shfl_xor(loss, off, 64);
        const int   ok = __shfl_xor(kk,   off, 64);
        if (ol < loss || (ol == loss && ok < kk)) { loss = ol; kk = ok; }
    }
    if (lane == 0) {
        const float fx = intr[0], cx = intr[2], fy = intr[4], cy = intr[5];
        const float dk = bdepth[box] + (0.1f * (float)kk - 3.0f);
        const float axv = (pc[box*2+0] - cx) / fx;
        const float ayv = (pc[box*2+1] - cy) / fy;
        out[box*3+0] = axv * dk;
        out[box*3+1] = ayv * dk + dims[box*3+1] * 0.5f;
        out[box*3+2] = dk;
    }
}

extern "C" void kernel_launch(void* const* d_in, const int* in_sizes, int n_in,
                              void* d_out, int out_size, void* d_ws, size_t ws_size,
                              hipStream_t stream) {
    const float* nocs  = (const float*)d_in[0];
    const float* dd    = (const float*)d_in[1];
    const int*   boxes = (const int*)d_in[2];
    const float* pc    = (const float*)d_in[3];
    const float* bd    = (const float*)d_in[4];
    const float* dims  = (const float*)d_in[5];
    const float* intr  = (const float*)d_in[6];
    float* out     = (float*)d_out;
    float* partial = (float*)d_ws;

    int S = SLICES;
    while (S > 1 && (size_t)NBOX * KCAND * S * sizeof(float) > ws_size) S >>= 1;

    loss_partial_kernel<<<dim3(S, NBOX, KGROUPS), THREADS, 0, stream>>>(
        nocs, dd, boxes, pc, bd, intr, partial, S);
    finalize_kernel<<<NBOX, 64, 0, stream>>>(
        partial, pc, bd, dims, intr, out, S);
}